// Round 3
// baseline (1778.907 us; speedup 1.0000x reference)
//
#include <hip/hip_runtime.h>
#include <cmath>

#define NN 50000
#define NE 800000
// int32-overflow boundary of the reference's argsort key (jax x64 disabled):
// key = dst*50000+src wraps for dst>42949, or dst==42949 && src>=33648.
#define DST_HI 42949
#define SRC_CUT 33648

// ---- degrees via atomic scatter (mirrors segment_sum exactly) ----
__global__ __launch_bounds__(256) void k_deg(const int* __restrict__ src, const int* __restrict__ dst,
                                             const float* __restrict__ w,
                                             float* dout, float* din, int* cnt) {
  int e = blockIdx.x * 256 + threadIdx.x;
  if (e >= NE) return;
  float we = w[e];
  atomicAdd(&dout[src[e]], we);
  atomicAdd(&din[dst[e]], we);
  atomicAdd(&cnt[dst[e]], 1);
}

// ---- single-block exclusive scan of cnt -> sp (sp[NN] = NE) ----
__global__ __launch_bounds__(1024) void k_scan(const int* __restrict__ cnt, int* __restrict__ sp) {
  __shared__ int tmp[1024];
  __shared__ int carry;
  const int tid = threadIdx.x;
  if (tid == 0) carry = 0;
  __syncthreads();
  for (int base = 0; base < NN; base += 1024) {
    int i = base + tid;
    int v = (i < NN) ? cnt[i] : 0;
    tmp[tid] = v;
    __syncthreads();
    for (int off = 1; off < 1024; off <<= 1) {
      int t = (tid >= off) ? tmp[tid - off] : 0;
      __syncthreads();
      tmp[tid] += t;
      __syncthreads();
    }
    if (i < NN) sp[i] = carry + tmp[tid] - v;  // exclusive + carry
    __syncthreads();
    if (tid == 0) carry += tmp[1023];
    __syncthreads();
  }
  if (tid == 0) sp[NN] = carry;
}

// ---- scatter edge ids into dst buckets (any order), then sort each bucket ----
__global__ __launch_bounds__(256) void k_bucket(const int* __restrict__ dst, const int* __restrict__ sp,
                                                int* __restrict__ fill, int* __restrict__ bucket) {
  int e = blockIdx.x * 256 + threadIdx.x;
  if (e >= NE) return;
  int d = dst[e];
  int slot = sp[d] + atomicAdd(&fill[d], 1);
  bucket[slot] = e;
}

// ascending edge-id within a dst bucket == ascending src  (bucket == argsort by true (dst,src))
__global__ __launch_bounds__(256) void k_sort(const int* __restrict__ sp, int* __restrict__ bucket) {
  int d = blockIdx.x * 256 + threadIdx.x;
  if (d >= NN) return;
  int b0 = sp[d], b1 = sp[d + 1];
  for (int i = b0 + 1; i < b1; ++i) {
    int v = bucket[i];
    int j = i - 1;
    while (j >= b0 && bucket[j] > v) { bucket[j + 1] = bucket[j]; --j; }
    bucket[j + 1] = v;
  }
}

// ---- rotation offset s0 = #edges with non-overflowing key:
//      all dst < DST_HI, plus src < SRC_CUT within dst == DST_HI's bucket ----
__global__ void k_s0(const int* __restrict__ sp, const int* __restrict__ bucket,
                     const int* __restrict__ src, int* __restrict__ s0) {
  if (threadIdx.x != 0 || blockIdx.x != 0) return;
  int b0 = sp[DST_HI], b1 = sp[DST_HI + 1];
  int c = b0;  // all edges with dst < DST_HI don't overflow
  for (int j = b0; j < b1; ++j)
    if (src[bucket[j]] < SRC_CUT) ++c;
  *s0 = c;
}

// ---- forward prop, faithful per-edge scatter: out[dst[e]] += x[src[e]]/dout[src[e]] ----
__global__ __launch_bounds__(256) void k_fwd(const int* __restrict__ src, const int* __restrict__ dst,
                                             const float* __restrict__ dout,
                                             const float* __restrict__ x, float* __restrict__ out) {
  int t = blockIdx.x * 256 + threadIdx.x;
  if (t >= NE * 8) return;
  int e = t >> 3, q = t & 7;
  int s = src[e], d = dst[e];
  float w = 1.0f / dout[s];
  const float4 xv = *(const float4*)&x[s * 32 + q * 4];
  float* o = &out[d * 32 + q * 4];
  atomicAdd(o + 0, w * xv.x);
  atomicAdd(o + 1, w * xv.y);
  atomicAdd(o + 2, w * xv.z);
  atomicAdd(o + 3, w * xv.w);
}

// ---- reverse prop with the jax int32-wrapped order (rotation by s0) and the positional norm quirk:
//      e = bucket[(j + s0) mod NE];  out[src[e]] += x[dst[e]] / din[src[j]] ----
__global__ __launch_bounds__(256) void k_rev(const int* __restrict__ src, const int* __restrict__ dst,
                                             const int* __restrict__ bucket, const int* __restrict__ s0p,
                                             const float* __restrict__ din,
                                             const float* __restrict__ x, float* __restrict__ out) {
  int t = blockIdx.x * 256 + threadIdx.x;
  if (t >= NE * 8) return;
  int j = t >> 3, q = t & 7;
  int idx = j + *s0p;
  if (idx >= NE) idx -= NE;
  int e = bucket[idx];
  float w = 1.0f / din[src[j]];   // quirk: norm indexed by UNROTATED position j
  const float4 xv = *(const float4*)&x[dst[e] * 32 + q * 4];
  float* o = &out[src[e] * 32 + q * 4];
  atomicAdd(o + 0, w * xv.x);
  atomicAdd(o + 1, w * xv.y);
  atomicAdd(o + 2, w * xv.z);
  atomicAdd(o + 3, w * xv.w);
}

// ---- Chebyshev step: A = 2*A - X, B = 2*B - X (in place) ----
__global__ __launch_bounds__(256) void k_cheb(const float* __restrict__ X,
                                              float* __restrict__ A, float* __restrict__ B) {
  int t = blockIdx.x * 256 + threadIdx.x;
  if (t >= NN * 8) return;
  const float4 xv = ((const float4*)X)[t];
  float4 a = ((float4*)A)[t];
  a.x = 2.f * a.x - xv.x; a.y = 2.f * a.y - xv.y; a.z = 2.f * a.z - xv.z; a.w = 2.f * a.w - xv.w;
  ((float4*)A)[t] = a;
  float4 b = ((float4*)B)[t];
  b.x = 2.f * b.x - xv.x; b.y = 2.f * b.y - xv.y; b.z = 2.f * b.z - xv.z; b.w = 2.f * b.w - xv.w;
  ((float4*)B)[t] = b;
}

// ---- effective weights (160 x 128): rows = [X|T1o|T1i|T2o|T2i]x32, cols 0..63=z, 64..127=h
//      W[i][k][c][f] flat = i*18432 + k*6144 + c*64 + f   (shape 2,3,96,64; only c<32 matters: H==0)
__global__ __launch_bounds__(256) void k_weff(const float* __restrict__ Wz, const float* __restrict__ Wh,
                                              float* __restrict__ Weff) {
  int idx = blockIdx.x * 256 + threadIdx.x;
  if (idx >= 160 * 128) return;
  int kk = idx >> 7, f = idx & 127;
  int blk = kk >> 5, c = kk & 31;
  const float* W = (f < 64) ? Wz : Wh;
  int fl = f & 63;
  float v;
  if (blk == 0)      v = W[c * 64 + fl] + W[18432 + c * 64 + fl];    // W[0,0] + W[1,0]
  else if (blk == 1) v = W[6144 + c * 64 + fl];                      // W[0,1]
  else if (blk == 2) v = W[18432 + 6144 + c * 64 + fl];              // W[1,1]
  else if (blk == 3) v = W[2 * 6144 + c * 64 + fl];                  // W[0,2]
  else               v = W[18432 + 2 * 6144 + c * 64 + fl];          // W[1,2]
  Weff[idx] = v;
}

// ---- simple GEMM + GRU epilogue: 16 rows/block, thread = (f in [0,64), rowgroup rg in [0,4)) ----
__global__ __launch_bounds__(256) void k_gemm(const float* __restrict__ X, const float* __restrict__ T1o,
                                              const float* __restrict__ T1i, const float* __restrict__ T2o,
                                              const float* __restrict__ T2i,
                                              const float* __restrict__ Weff,
                                              const float* __restrict__ bz, const float* __restrict__ bh,
                                              float* __restrict__ out) {
  __shared__ float Fs[16][160];
  const int tid = threadIdx.x;
  const int rb = blockIdx.x * 16;
  const float* bases[5] = {X, T1o, T1i, T2o, T2i};
  for (int i = 0; i < 10; ++i) {           // 16*160 = 2560 = 10*256 scalar stages
    int idx = tid + i * 256;
    int row = idx / 160, c = idx % 160;
    int gr = rb + row;
    float v = 0.f;
    if (gr < NN) v = bases[c >> 5][gr * 32 + (c & 31)];
    Fs[row][c] = v;
  }
  __syncthreads();
  const int f = tid & 63, rg = tid >> 6;
  float az[4] = {0.f, 0.f, 0.f, 0.f}, ah[4] = {0.f, 0.f, 0.f, 0.f};
  for (int k = 0; k < 160; ++k) {
    float wz = Weff[k * 128 + f];
    float wh = Weff[k * 128 + 64 + f];
#pragma unroll
    for (int i = 0; i < 4; ++i) {
      float a = Fs[rg + 4 * i][k];
      az[i] += a * wz;
      ah[i] += a * wh;
    }
  }
  const float bzf = bz[f], bhf = bh[f];
#pragma unroll
  for (int i = 0; i < 4; ++i) {
    int r = rb + rg + 4 * i;
    if (r < NN) {
      float z = 1.f / (1.f + expf(-(az[i] + bzf)));
      float h = tanhf(ah[i] + bhf);
      out[r * 64 + f] = (1.f - z) * h;   // Z*H + (1-Z)*H_tilde with H = 0
    }
  }
}

// ---------------- launch ----------------
extern "C" void kernel_launch(void* const* d_in, const int* in_sizes, int n_in,
                              void* d_out, int out_size, void* d_ws, size_t ws_size,
                              hipStream_t stream) {
  const float* X  = (const float*)d_in[0];
  const int*   ei = (const int*)d_in[1];
  const float* ew = (const float*)d_in[2];
  const float* Wz = (const float*)d_in[3];
  const float* bz = (const float*)d_in[4];
  const float* Wh = (const float*)d_in[7];
  const float* bh = (const float*)d_in[8];
  float* out = (float*)d_out;
  const int* src = ei;
  const int* dst = ei + NE;

  char* p = (char*)d_ws;
  auto alloc = [&](size_t bytes) -> char* {
    char* r = p;
    p += (bytes + 255) & ~(size_t)255;
    return r;
  };
  float* T1o    = (float*)alloc((size_t)NN * 32 * 4);
  float* T1i    = (float*)alloc((size_t)NN * 32 * 4);
  float* P2o    = (float*)alloc((size_t)NN * 32 * 4);   // becomes T2o after k_cheb
  float* P2i    = (float*)alloc((size_t)NN * 32 * 4);   // becomes T2i
  int*   bucket = (int*)alloc((size_t)NE * 4);
  int*   sp     = (int*)alloc((NN + 1) * 4);
  int*   cnt    = (int*)alloc(NN * 4);
  int*   fill   = (int*)alloc(NN * 4);
  float* dout   = (float*)alloc(NN * 4);
  float* din    = (float*)alloc(NN * 4);
  float* Weff   = (float*)alloc(160 * 128 * 4);
  int*   s0     = (int*)alloc(4);

  hipMemsetAsync(T1o, 0, (size_t)NN * 32 * 4, stream);
  hipMemsetAsync(T1i, 0, (size_t)NN * 32 * 4, stream);
  hipMemsetAsync(P2o, 0, (size_t)NN * 32 * 4, stream);
  hipMemsetAsync(P2i, 0, (size_t)NN * 32 * 4, stream);
  hipMemsetAsync(cnt, 0, NN * 4, stream);
  hipMemsetAsync(fill, 0, NN * 4, stream);
  hipMemsetAsync(dout, 0, NN * 4, stream);
  hipMemsetAsync(din, 0, NN * 4, stream);

  k_deg<<<3125, 256, 0, stream>>>(src, dst, ew, dout, din, cnt);
  k_scan<<<1, 1024, 0, stream>>>(cnt, sp);
  k_bucket<<<3125, 256, 0, stream>>>(dst, sp, fill, bucket);
  k_sort<<<196, 256, 0, stream>>>(sp, bucket);
  k_s0<<<1, 64, 0, stream>>>(sp, bucket, src, s0);

  // round 1: T1o = Pf(X), T1i = Pr(X)
  k_fwd<<<25000, 256, 0, stream>>>(src, dst, dout, X, T1o);
  k_rev<<<25000, 256, 0, stream>>>(src, dst, bucket, s0, din, X, T1i);
  // round 2 raw: P2o = Pf(T1o), P2i = Pr(T1i)
  k_fwd<<<25000, 256, 0, stream>>>(src, dst, dout, T1o, P2o);
  k_rev<<<25000, 256, 0, stream>>>(src, dst, bucket, s0, din, T1i, P2i);
  // T2 = 2*P2 - X
  k_cheb<<<1563, 256, 0, stream>>>(X, P2o, P2i);

  k_weff<<<80, 256, 0, stream>>>(Wz, Wh, Weff);
  k_gemm<<<3125, 256, 0, stream>>>(X, T1o, T1i, P2o, P2i, Weff, bz, bh, out);
}

// Round 4
// 612.476 us; speedup vs baseline: 2.9045x; 2.9045x over previous
//
#include <hip/hip_runtime.h>
#include <cmath>

#define NN 50000
#define NE 800000
// int32-overflow boundary of the reference's argsort key (jax x64 disabled):
// key = dst*50000+src wraps for dst>42949, or dst==42949 && src>=33648.
// VERIFIED round 3: jax order = rotate(bucket, s0), norm indexed by UNROTATED j.
#define DST_HI 42949
#define SRC_CUT 33648

// ---- degrees via atomic scatter ----
__global__ __launch_bounds__(256) void k_deg(const int* __restrict__ src, const int* __restrict__ dst,
                                             const float* __restrict__ w,
                                             float* dout, float* din, int* cnt) {
  int e = blockIdx.x * 256 + threadIdx.x;
  if (e >= NE) return;
  float we = w[e];
  atomicAdd(&dout[src[e]], we);
  atomicAdd(&din[dst[e]], we);
  atomicAdd(&cnt[dst[e]], 1);
}

// ---- CSR row_ptr by src via binary search (src sorted ascending) ----
__global__ __launch_bounds__(256) void k_rowptr(const int* __restrict__ src, int* __restrict__ rptr) {
  int i = blockIdx.x * 256 + threadIdx.x;
  if (i > NN) return;
  int lo = 0, hi = NE;
  while (lo < hi) { int m = (lo + hi) >> 1; if (src[m] < i) lo = m + 1; else hi = m; }
  rptr[i] = lo;
}

// ---- single-block exclusive scan of cnt -> sp (sp[NN] = NE) ----
__global__ __launch_bounds__(1024) void k_scan(const int* __restrict__ cnt, int* __restrict__ sp) {
  __shared__ int tmp[1024];
  __shared__ int carry;
  const int tid = threadIdx.x;
  if (tid == 0) carry = 0;
  __syncthreads();
  for (int base = 0; base < NN; base += 1024) {
    int i = base + tid;
    int v = (i < NN) ? cnt[i] : 0;
    tmp[tid] = v;
    __syncthreads();
    for (int off = 1; off < 1024; off <<= 1) {
      int t = (tid >= off) ? tmp[tid - off] : 0;
      __syncthreads();
      tmp[tid] += t;
      __syncthreads();
    }
    if (i < NN) sp[i] = carry + tmp[tid] - v;
    __syncthreads();
    if (tid == 0) carry += tmp[1023];
    __syncthreads();
  }
  if (tid == 0) sp[NN] = carry;
}

// ---- scatter edge ids into dst buckets, then sort each bucket (== argsort by true (dst,src)) ----
__global__ __launch_bounds__(256) void k_bucket(const int* __restrict__ dst, const int* __restrict__ sp,
                                                int* __restrict__ fill, int* __restrict__ bucket) {
  int e = blockIdx.x * 256 + threadIdx.x;
  if (e >= NE) return;
  int d = dst[e];
  int slot = sp[d] + atomicAdd(&fill[d], 1);
  bucket[slot] = e;
}

__global__ __launch_bounds__(256) void k_sort(const int* __restrict__ sp, int* __restrict__ bucket) {
  int d = blockIdx.x * 256 + threadIdx.x;
  if (d >= NN) return;
  int b0 = sp[d], b1 = sp[d + 1];
  for (int i = b0 + 1; i < b1; ++i) {
    int v = bucket[i];
    int j = i - 1;
    while (j >= b0 && bucket[j] > v) { bucket[j + 1] = bucket[j]; --j; }
    bucket[j + 1] = v;
  }
}

// ---- rotation offset s0 = #edges with non-overflowing int32 key ----
__global__ void k_s0(const int* __restrict__ sp, const int* __restrict__ bucket,
                     const int* __restrict__ src, int* __restrict__ s0) {
  if (threadIdx.x != 0 || blockIdx.x != 0) return;
  int b0 = sp[DST_HI], b1 = sp[DST_HI + 1];
  int c = b0;
  for (int j = b0; j < b1; ++j)
    if (src[bucket[j]] < SRC_CUT) ++c;
  *s0 = c;
}

// ---- per-edge arrays for gather props:
//   fwd (CSC by dst bucket): col_fwd[j] = src[bucket[j]], nrm_fwd[j] = 1/dout[col_fwd[j]]
//   rev (CSR by src): rnrm[bucket[(j+s0)%NE]] = 1/din[src[j]]  (rotation bijection, verified) ----
__global__ __launch_bounds__(256) void k_edge(const int* __restrict__ bucket, const int* __restrict__ src,
                                              const int* __restrict__ s0p,
                                              const float* __restrict__ dout, const float* __restrict__ din,
                                              int* __restrict__ col_fwd, float* __restrict__ nrm_fwd,
                                              float* __restrict__ rnrm) {
  int j = blockIdx.x * 256 + threadIdx.x;
  if (j >= NE) return;
  int e = bucket[j];
  int s = src[e];
  col_fwd[j] = s;
  nrm_fwd[j] = 1.0f / dout[s];
  int idx = j + *s0p;
  if (idx >= NE) idx -= NE;
  rnrm[bucket[idx]] = 1.0f / din[src[j]];
}

// ---- gather prop (row-gather SpMM, 32 ch): 8 lanes/row, float4/lane.
//      out = mul*acc - sub   (sub==nullptr -> out = acc) ----
__global__ __launch_bounds__(256) void k_prop(const float* __restrict__ in,
                                              const int* __restrict__ rp, const int* __restrict__ cols,
                                              const float* __restrict__ nrm,
                                              const float* __restrict__ sub, float mul,
                                              float* __restrict__ out) {
  int t = blockIdx.x * 256 + threadIdx.x;
  int r = t >> 3;
  if (r >= NN) return;
  int c4 = (t & 7) * 4;
  int b = rp[r], e = rp[r + 1];
  float ax = 0.f, ay = 0.f, az = 0.f, aw = 0.f;
  for (int p = b; p < e; ++p) {
    int col = cols[p];       // 8 lanes same addr -> broadcast
    float w = nrm[p];
    const float4 xv = *(const float4*)&in[col * 32 + c4];
    ax += w * xv.x; ay += w * xv.y; az += w * xv.z; aw += w * xv.w;
  }
  float4 o;
  if (sub) {
    const float4 s = *(const float4*)&sub[r * 32 + c4];
    o.x = mul * ax - s.x; o.y = mul * ay - s.y; o.z = mul * az - s.z; o.w = mul * aw - s.w;
  } else {
    o.x = ax; o.y = ay; o.z = az; o.w = aw;
  }
  *(float4*)&out[r * 32 + c4] = o;
}

// ---- effective weights (160 x 128): rows = [X|T1o|T1i|T2o|T2i]x32, cols 0..63=z, 64..127=h ----
__global__ __launch_bounds__(256) void k_weff(const float* __restrict__ Wz, const float* __restrict__ Wh,
                                              float* __restrict__ Weff) {
  int idx = blockIdx.x * 256 + threadIdx.x;
  if (idx >= 160 * 128) return;
  int kk = idx >> 7, f = idx & 127;
  int blk = kk >> 5, c = kk & 31;
  const float* W = (f < 64) ? Wz : Wh;
  int fl = f & 63;
  float v;
  if (blk == 0)      v = W[c * 64 + fl] + W[18432 + c * 64 + fl];
  else if (blk == 1) v = W[6144 + c * 64 + fl];
  else if (blk == 2) v = W[18432 + 6144 + c * 64 + fl];
  else if (blk == 3) v = W[2 * 6144 + c * 64 + fl];
  else               v = W[18432 + 2 * 6144 + c * 64 + fl];
  Weff[idx] = v;
}

// ---- GEMM + GRU epilogue (validated round 3): 16 rows/block ----
__global__ __launch_bounds__(256) void k_gemm(const float* __restrict__ X, const float* __restrict__ T1o,
                                              const float* __restrict__ T1i, const float* __restrict__ T2o,
                                              const float* __restrict__ T2i,
                                              const float* __restrict__ Weff,
                                              const float* __restrict__ bz, const float* __restrict__ bh,
                                              float* __restrict__ out) {
  __shared__ float Fs[16][160];
  const int tid = threadIdx.x;
  const int rb = blockIdx.x * 16;
  const float* bases[5] = {X, T1o, T1i, T2o, T2i};
  for (int i = 0; i < 10; ++i) {
    int idx = tid + i * 256;
    int row = idx / 160, c = idx % 160;
    int gr = rb + row;
    float v = 0.f;
    if (gr < NN) v = bases[c >> 5][gr * 32 + (c & 31)];
    Fs[row][c] = v;
  }
  __syncthreads();
  const int f = tid & 63, rg = tid >> 6;
  float az[4] = {0.f, 0.f, 0.f, 0.f}, ah[4] = {0.f, 0.f, 0.f, 0.f};
  for (int k = 0; k < 160; ++k) {
    float wz = Weff[k * 128 + f];
    float wh = Weff[k * 128 + 64 + f];
#pragma unroll
    for (int i = 0; i < 4; ++i) {
      float a = Fs[rg + 4 * i][k];
      az[i] += a * wz;
      ah[i] += a * wh;
    }
  }
  const float bzf = bz[f], bhf = bh[f];
#pragma unroll
  for (int i = 0; i < 4; ++i) {
    int r = rb + rg + 4 * i;
    if (r < NN) {
      float z = 1.f / (1.f + expf(-(az[i] + bzf)));
      float h = tanhf(ah[i] + bhf);
      out[r * 64 + f] = (1.f - z) * h;
    }
  }
}

// ---------------- launch ----------------
extern "C" void kernel_launch(void* const* d_in, const int* in_sizes, int n_in,
                              void* d_out, int out_size, void* d_ws, size_t ws_size,
                              hipStream_t stream) {
  const float* X  = (const float*)d_in[0];
  const int*   ei = (const int*)d_in[1];
  const float* ew = (const float*)d_in[2];
  const float* Wz = (const float*)d_in[3];
  const float* bz = (const float*)d_in[4];
  const float* Wh = (const float*)d_in[7];
  const float* bh = (const float*)d_in[8];
  float* out = (float*)d_out;
  const int* src = ei;
  const int* dst = ei + NE;

  char* p = (char*)d_ws;
  auto alloc = [&](size_t bytes) -> char* {
    char* r = p;
    p += (bytes + 255) & ~(size_t)255;
    return r;
  };
  float* T1o     = (float*)alloc((size_t)NN * 32 * 4);
  float* T1i     = (float*)alloc((size_t)NN * 32 * 4);
  float* T2o     = (float*)alloc((size_t)NN * 32 * 4);
  float* T2i     = (float*)alloc((size_t)NN * 32 * 4);
  int*   bucket  = (int*)alloc((size_t)NE * 4);
  int*   col_fwd = (int*)alloc((size_t)NE * 4);
  float* nrm_fwd = (float*)alloc((size_t)NE * 4);
  float* rnrm    = (float*)alloc((size_t)NE * 4);
  int*   sp      = (int*)alloc((NN + 1) * 4);
  int*   rptr    = (int*)alloc((NN + 1) * 4);
  int*   cnt     = (int*)alloc(NN * 4);
  int*   fill    = (int*)alloc(NN * 4);
  float* dout    = (float*)alloc(NN * 4);
  float* din     = (float*)alloc(NN * 4);
  float* Weff    = (float*)alloc(160 * 128 * 4);
  int*   s0      = (int*)alloc(4);

  hipMemsetAsync(cnt, 0, NN * 4, stream);
  hipMemsetAsync(fill, 0, NN * 4, stream);
  hipMemsetAsync(dout, 0, NN * 4, stream);
  hipMemsetAsync(din, 0, NN * 4, stream);

  k_deg<<<3125, 256, 0, stream>>>(src, dst, ew, dout, din, cnt);
  k_rowptr<<<196, 256, 0, stream>>>(src, rptr);
  k_scan<<<1, 1024, 0, stream>>>(cnt, sp);
  k_bucket<<<3125, 256, 0, stream>>>(dst, sp, fill, bucket);
  k_sort<<<196, 256, 0, stream>>>(sp, bucket);
  k_s0<<<1, 64, 0, stream>>>(sp, bucket, src, s0);
  k_edge<<<3125, 256, 0, stream>>>(bucket, src, s0, dout, din, col_fwd, nrm_fwd, rnrm);

  // T1o = Pf(X) (CSC gather), T1i = Pr(X) (CSR gather) — no atomics
  k_prop<<<1563, 256, 0, stream>>>(X, sp, col_fwd, nrm_fwd, nullptr, 1.f, T1o);
  k_prop<<<1563, 256, 0, stream>>>(X, rptr, dst, rnrm, nullptr, 1.f, T1i);
  // T2 = 2*P(T1) - X (fused Chebyshev)
  k_prop<<<1563, 256, 0, stream>>>(T1o, sp, col_fwd, nrm_fwd, X, 2.f, T2o);
  k_prop<<<1563, 256, 0, stream>>>(T1i, rptr, dst, rnrm, X, 2.f, T2i);

  k_weff<<<80, 256, 0, stream>>>(Wz, Wh, Weff);
  k_gemm<<<3125, 256, 0, stream>>>(X, T1o, T1i, T2o, T2i, Weff, bz, bh, out);
}

// Round 5
// 387.988 us; speedup vs baseline: 4.5850x; 1.5786x over previous
//
#include <hip/hip_runtime.h>
#include <cmath>

#define NN 50000
#define NE 800000
// int32-overflow boundary of the reference's argsort key (jax x64 disabled):
// key = dst*50000+src wraps for dst>42949, or dst==42949 && src>=33648.
// VERIFIED round 3: jax order = rotate(bucket, s0), norm indexed by UNROTATED j.
#define DST_HI 42949
#define SRC_CUT 33648

// ---- CSR row_ptr by src via binary search (src sorted ascending) ----
__global__ __launch_bounds__(256) void k_rowptr(const int* __restrict__ src, int* __restrict__ rptr) {
  int i = blockIdx.x * 256 + threadIdx.x;
  if (i > NN) return;
  int lo = 0, hi = NE;
  while (lo < hi) { int m = (lo + hi) >> 1; if (src[m] < i) lo = m + 1; else hi = m; }
  rptr[i] = lo;
}

// ---- dout: contiguous segment sum over src-CSR, 8 lanes/node, no atomics ----
__global__ __launch_bounds__(256) void k_degout(const int* __restrict__ rptr, const float* __restrict__ w,
                                                float* __restrict__ dout) {
  int t = blockIdx.x * 256 + threadIdx.x;
  int r = t >> 3;
  if (r >= NN) return;
  int lane = t & 7;
  int b = rptr[r], e = rptr[r + 1];
  float a = 0.f;
  for (int p = b + lane; p < e; p += 8) a += w[p];
  a += __shfl_down(a, 4, 8);
  a += __shfl_down(a, 2, 8);
  a += __shfl_down(a, 1, 8);
  if (lane == 0) dout[r] = a;
}

// ---- dst histogram (the one unavoidable atomic pass: 1 atomic/edge) ----
__global__ __launch_bounds__(256) void k_cnt(const int* __restrict__ dst, int* __restrict__ cnt) {
  int e = blockIdx.x * 256 + threadIdx.x;
  if (e >= NE) return;
  atomicAdd(&cnt[dst[e]], 1);
}

// ---- 3-kernel exclusive scan of cnt -> sp (sp[NN] = NE) ----
__global__ void k_scan1(const int* __restrict__ cnt, int* __restrict__ outp, int* __restrict__ partials) {
  __shared__ int tmp[1024];
  int i = blockIdx.x * 1024 + threadIdx.x;
  int v = (i < NN) ? cnt[i] : 0;
  tmp[threadIdx.x] = v;
  __syncthreads();
  for (int off = 1; off < 1024; off <<= 1) {
    int t = (threadIdx.x >= (unsigned)off) ? tmp[threadIdx.x - off] : 0;
    __syncthreads();
    tmp[threadIdx.x] += t;
    __syncthreads();
  }
  if (i < NN) outp[i] = tmp[threadIdx.x] - v;  // exclusive
  if (threadIdx.x == 1023) partials[blockIdx.x] = tmp[1023];
}

__global__ void k_scan2(int* __restrict__ partials, int nb) {
  if (threadIdx.x == 0 && blockIdx.x == 0) {
    int s = 0;
    for (int i = 0; i < nb; ++i) { int v = partials[i]; partials[i] = s; s += v; }
  }
}

__global__ __launch_bounds__(256) void k_scan3(int* __restrict__ outp, const int* __restrict__ partials) {
  int i = blockIdx.x * 256 + threadIdx.x;
  if (i < NN) outp[i] += partials[i >> 10];
  else if (i == NN) outp[i] = NE;
}

// ---- scatter edge ids into dst buckets, then sort each bucket (== argsort by true (dst,src)) ----
__global__ __launch_bounds__(256) void k_bucket(const int* __restrict__ dst, const int* __restrict__ sp,
                                                int* __restrict__ fill, int* __restrict__ bucket) {
  int e = blockIdx.x * 256 + threadIdx.x;
  if (e >= NE) return;
  int d = dst[e];
  int slot = sp[d] + atomicAdd(&fill[d], 1);
  bucket[slot] = e;
}

__global__ __launch_bounds__(256) void k_sort(const int* __restrict__ sp, int* __restrict__ bucket) {
  int d = blockIdx.x * 256 + threadIdx.x;
  if (d >= NN) return;
  int b0 = sp[d], b1 = sp[d + 1];
  for (int i = b0 + 1; i < b1; ++i) {
    int v = bucket[i];
    int j = i - 1;
    while (j >= b0 && bucket[j] > v) { bucket[j + 1] = bucket[j]; --j; }
    bucket[j + 1] = v;
  }
}

// ---- din: gather segment sum over dst-buckets (order-invariant), 8 lanes/node, no atomics ----
__global__ __launch_bounds__(256) void k_din(const int* __restrict__ sp, const int* __restrict__ bucket,
                                             const float* __restrict__ w, float* __restrict__ din) {
  int t = blockIdx.x * 256 + threadIdx.x;
  int r = t >> 3;
  if (r >= NN) return;
  int lane = t & 7;
  int b = sp[r], e = sp[r + 1];
  float a = 0.f;
  for (int j = b + lane; j < e; j += 8) a += w[bucket[j]];
  a += __shfl_down(a, 4, 8);
  a += __shfl_down(a, 2, 8);
  a += __shfl_down(a, 1, 8);
  if (lane == 0) din[r] = a;
}

// ---- rotation offset s0 = #edges with non-overflowing int32 key ----
__global__ void k_s0(const int* __restrict__ sp, const int* __restrict__ bucket,
                     const int* __restrict__ src, int* __restrict__ s0) {
  if (threadIdx.x != 0 || blockIdx.x != 0) return;
  int b0 = sp[DST_HI], b1 = sp[DST_HI + 1];
  int c = b0;
  for (int j = b0; j < b1; ++j)
    if (src[bucket[j]] < SRC_CUT) ++c;
  *s0 = c;
}

// ---- per-edge arrays for gather props:
//   fwd (CSC by dst bucket): col_fwd[j] = src[bucket[j]], nrm_fwd[j] = 1/dout[col_fwd[j]]
//   rev (CSR by src): rnrm[bucket[(j+s0)%NE]] = 1/din[src[j]]  (rotation bijection, verified) ----
__global__ __launch_bounds__(256) void k_edge(const int* __restrict__ bucket, const int* __restrict__ src,
                                              const int* __restrict__ s0p,
                                              const float* __restrict__ dout, const float* __restrict__ din,
                                              int* __restrict__ col_fwd, float* __restrict__ nrm_fwd,
                                              float* __restrict__ rnrm) {
  int j = blockIdx.x * 256 + threadIdx.x;
  if (j >= NE) return;
  int e = bucket[j];
  int s = src[e];
  col_fwd[j] = s;
  nrm_fwd[j] = 1.0f / dout[s];
  int idx = j + *s0p;
  if (idx >= NE) idx -= NE;
  rnrm[bucket[idx]] = 1.0f / din[src[j]];
}

// ---- fused pair of gather props (A and B independent): 8 lanes/row, float4/lane.
//      out = mul*acc - sub   (sub==nullptr -> out = acc) ----
__global__ __launch_bounds__(256) void k_prop2(const float* __restrict__ inA, const int* __restrict__ rpA,
                                               const int* __restrict__ colsA, const float* __restrict__ nrmA,
                                               float* __restrict__ outA,
                                               const float* __restrict__ inB, const int* __restrict__ rpB,
                                               const int* __restrict__ colsB, const float* __restrict__ nrmB,
                                               float* __restrict__ outB,
                                               const float* __restrict__ sub, float mul) {
  int t = blockIdx.x * 256 + threadIdx.x;
  const int half = NN * 8;
  const float* in; const int* rp; const int* cols; const float* nrm; float* out;
  if (t < half) { in = inA; rp = rpA; cols = colsA; nrm = nrmA; out = outA; }
  else          { in = inB; rp = rpB; cols = colsB; nrm = nrmB; out = outB; t -= half; }
  int r = t >> 3;
  if (r >= NN) return;
  int c4 = (t & 7) * 4;
  int b = rp[r], e = rp[r + 1];
  float ax = 0.f, ay = 0.f, az = 0.f, aw = 0.f;
  for (int p = b; p < e; ++p) {
    int col = cols[p];       // 8 lanes same addr -> broadcast
    float w = nrm[p];
    const float4 xv = *(const float4*)&in[col * 32 + c4];
    ax += w * xv.x; ay += w * xv.y; az += w * xv.z; aw += w * xv.w;
  }
  float4 o;
  if (sub) {
    const float4 s = *(const float4*)&sub[r * 32 + c4];
    o.x = mul * ax - s.x; o.y = mul * ay - s.y; o.z = mul * az - s.z; o.w = mul * aw - s.w;
  } else {
    o.x = ax; o.y = ay; o.z = az; o.w = aw;
  }
  *(float4*)&out[r * 32 + c4] = o;
}

// ---- effective weights (160 x 128): rows = [X|T1o|T1i|T2o|T2i]x32, cols 0..63=z, 64..127=h ----
__global__ __launch_bounds__(256) void k_weff(const float* __restrict__ Wz, const float* __restrict__ Wh,
                                              float* __restrict__ Weff) {
  int idx = blockIdx.x * 256 + threadIdx.x;
  if (idx >= 160 * 128) return;
  int kk = idx >> 7, f = idx & 127;
  int blk = kk >> 5, c = kk & 31;
  const float* W = (f < 64) ? Wz : Wh;
  int fl = f & 63;
  float v;
  if (blk == 0)      v = W[c * 64 + fl] + W[18432 + c * 64 + fl];
  else if (blk == 1) v = W[6144 + c * 64 + fl];
  else if (blk == 2) v = W[18432 + 6144 + c * 64 + fl];
  else if (blk == 3) v = W[2 * 6144 + c * 64 + fl];
  else               v = W[18432 + 2 * 6144 + c * 64 + fl];
  Weff[idx] = v;
}

// ---- GEMM + GRU epilogue (validated): 16 rows/block ----
__global__ __launch_bounds__(256) void k_gemm(const float* __restrict__ X, const float* __restrict__ T1o,
                                              const float* __restrict__ T1i, const float* __restrict__ T2o,
                                              const float* __restrict__ T2i,
                                              const float* __restrict__ Weff,
                                              const float* __restrict__ bz, const float* __restrict__ bh,
                                              float* __restrict__ out) {
  __shared__ float Fs[16][160];
  const int tid = threadIdx.x;
  const int rb = blockIdx.x * 16;
  const float* bases[5] = {X, T1o, T1i, T2o, T2i};
  for (int i = 0; i < 10; ++i) {
    int idx = tid + i * 256;
    int row = idx / 160, c = idx % 160;
    int gr = rb + row;
    float v = 0.f;
    if (gr < NN) v = bases[c >> 5][gr * 32 + (c & 31)];
    Fs[row][c] = v;
  }
  __syncthreads();
  const int f = tid & 63, rg = tid >> 6;
  float az[4] = {0.f, 0.f, 0.f, 0.f}, ah[4] = {0.f, 0.f, 0.f, 0.f};
  for (int k = 0; k < 160; ++k) {
    float wz = Weff[k * 128 + f];
    float wh = Weff[k * 128 + 64 + f];
#pragma unroll
    for (int i = 0; i < 4; ++i) {
      float a = Fs[rg + 4 * i][k];
      az[i] += a * wz;
      ah[i] += a * wh;
    }
  }
  const float bzf = bz[f], bhf = bh[f];
#pragma unroll
  for (int i = 0; i < 4; ++i) {
    int r = rb + rg + 4 * i;
    if (r < NN) {
      float z = 1.f / (1.f + expf(-(az[i] + bzf)));
      float h = tanhf(ah[i] + bhf);
      out[r * 64 + f] = (1.f - z) * h;
    }
  }
}

// ---------------- launch ----------------
extern "C" void kernel_launch(void* const* d_in, const int* in_sizes, int n_in,
                              void* d_out, int out_size, void* d_ws, size_t ws_size,
                              hipStream_t stream) {
  const float* X  = (const float*)d_in[0];
  const int*   ei = (const int*)d_in[1];
  const float* ew = (const float*)d_in[2];
  const float* Wz = (const float*)d_in[3];
  const float* bz = (const float*)d_in[4];
  const float* Wh = (const float*)d_in[7];
  const float* bh = (const float*)d_in[8];
  float* out = (float*)d_out;
  const int* src = ei;
  const int* dst = ei + NE;

  char* p = (char*)d_ws;
  auto alloc = [&](size_t bytes) -> char* {
    char* r = p;
    p += (bytes + 255) & ~(size_t)255;
    return r;
  };
  float* T1o     = (float*)alloc((size_t)NN * 32 * 4);
  float* T1i     = (float*)alloc((size_t)NN * 32 * 4);
  float* T2o     = (float*)alloc((size_t)NN * 32 * 4);
  float* T2i     = (float*)alloc((size_t)NN * 32 * 4);
  int*   bucket  = (int*)alloc((size_t)NE * 4);
  int*   col_fwd = (int*)alloc((size_t)NE * 4);
  float* nrm_fwd = (float*)alloc((size_t)NE * 4);
  float* rnrm    = (float*)alloc((size_t)NE * 4);
  int*   sp      = (int*)alloc((NN + 1) * 4);
  int*   rptr    = (int*)alloc((NN + 1) * 4);
  int*   cnt     = (int*)alloc(NN * 4);
  int*   fill    = (int*)alloc(NN * 4);
  int*   partial = (int*)alloc(64 * 4);
  float* dout    = (float*)alloc(NN * 4);
  float* din     = (float*)alloc(NN * 4);
  float* Weff    = (float*)alloc(160 * 128 * 4);
  int*   s0      = (int*)alloc(4);

  hipMemsetAsync(cnt, 0, NN * 4, stream);
  hipMemsetAsync(fill, 0, NN * 4, stream);

  k_rowptr<<<196, 256, 0, stream>>>(src, rptr);
  k_degout<<<1563, 256, 0, stream>>>(rptr, ew, dout);
  k_cnt<<<3125, 256, 0, stream>>>(dst, cnt);
  k_scan1<<<49, 1024, 0, stream>>>(cnt, sp, partial);
  k_scan2<<<1, 64, 0, stream>>>(partial, 49);
  k_scan3<<<196, 256, 0, stream>>>(sp, partial);
  k_bucket<<<3125, 256, 0, stream>>>(dst, sp, fill, bucket);
  k_sort<<<196, 256, 0, stream>>>(sp, bucket);
  k_din<<<1563, 256, 0, stream>>>(sp, bucket, ew, din);
  k_s0<<<1, 64, 0, stream>>>(sp, bucket, src, s0);
  k_edge<<<3125, 256, 0, stream>>>(bucket, src, s0, dout, din, col_fwd, nrm_fwd, rnrm);

  // T1o = Pf(X) (CSC gather), T1i = Pr(X) (CSR gather) — fused, no atomics
  k_prop2<<<3125, 256, 0, stream>>>(X, sp, col_fwd, nrm_fwd, T1o,
                                    X, rptr, dst, rnrm, T1i, nullptr, 1.f);
  // T2 = 2*P(T1) - X (fused Chebyshev), pair fused
  k_prop2<<<3125, 256, 0, stream>>>(T1o, sp, col_fwd, nrm_fwd, T2o,
                                    T1i, rptr, dst, rnrm, T2i, X, 2.f);

  k_weff<<<80, 256, 0, stream>>>(Wz, Wh, Weff);
  k_gemm<<<3125, 256, 0, stream>>>(X, T1o, T1i, T2o, T2i, Weff, bz, bh, out);
}